// Round 1
// baseline (11846.333 us; speedup 1.0000x reference)
//
#include <hip/hip_runtime.h>
#include <math.h>

#define BATCH 512
#define TT    128
#define FF    64
#define UU    1024
#define ZZ    4096
#define OS    32
#define KTOT  1088
#define NCHW  17            // warmup K chunks of 64 (0 = x, 1..16 = h)
#define NCHD  16            // decode K chunks of 64 (h only, K=1024)
#define CROW  72            // A LDS row stride in f16 (64 + 8 pad = 144 B)
#define CBUF  (32 * CROW)   // 2304 f16 = 4608 B per A chunk buffer (BM=32)
#define NKBW  68            // warmup k16 blocks per n-tile (1088/16)
#define NKBD  64            // decode k16 blocks per n-tile (1024/16)

typedef _Float16 f16x8 __attribute__((ext_vector_type(8)));
typedef float f32x16 __attribute__((ext_vector_type(16)));

__device__ __forceinline__ float sigf(float x) { return 1.0f / (1.0f + expf(-x)); }

// ---------------------------------------------------------------------------
// wconv: [Wk;Wr] (1088x4096 fp32) -> f16 fragment-linear, gate-interleaved
// ---------------------------------------------------------------------------
__global__ __launch_bounds__(256) void wconv(
    const float* __restrict__ Wk, const float* __restrict__ Wr,
    _Float16* __restrict__ WT)
{
    __shared__ float T[32][129];
    const int k0 = blockIdx.x * 32;   // 34
    const int n0 = blockIdx.y * 128;  // 32
    const int u0 = n0 >> 2;
    const int t = threadIdx.x;
    #pragma unroll
    for (int i = 0; i < 16; ++i) {
        int idx = t + i * 256;
        int u = idx & 31, k = (idx >> 5) & 31, g = idx >> 10;
        int krow = k0 + k;
        int col = g * UU + u0 + u;
        float wv = (krow < FF) ? Wk[(size_t)krow * ZZ + col]
                               : Wr[(size_t)(krow - FF) * ZZ + col];
        T[k][u * 4 + g] = wv;
    }
    __syncthreads();
    #pragma unroll
    for (int i = 0; i < 16; ++i) {
        int idx = t + i * 256;
        int k = idx & 31, np = idx >> 5;
        int r = n0 + np, kk = k0 + k;
        size_t o = ((size_t)(r >> 5) * NKBW + (kk >> 4)) * 512
                 + (size_t)((((kk >> 3) & 1) * 32 + (r & 31)) * 8 + (kk & 7));
        WT[o] = (_Float16)T[k][np];
    }
}

// ---------------------------------------------------------------------------
// wfus: WT2 = Wr + Wd@Wk (1024x4096), fragment-linear f16 (NKBD blocks/n-tile)
// ---------------------------------------------------------------------------
__global__ __launch_bounds__(256) void wfus(
    const float* __restrict__ Wk, const float* __restrict__ Wr,
    const float* __restrict__ Wd, _Float16* __restrict__ WT2)
{
    __shared__ float Wkk[64][128];    // [f][np]
    __shared__ float Wdd[32][65];     // [k][f], padded
    const int k0 = blockIdx.x * 32;   // 32 (u-rows)
    const int n0 = blockIdx.y * 128;  // 32
    const int u0 = n0 >> 2;
    const int t = threadIdx.x;
    #pragma unroll
    for (int i = 0; i < 32; ++i) {
        int idx = t + i * 256;        // 8192 = 64 f x 128 np
        int f = idx >> 7, np = idx & 127;
        int col = (np & 3) * UU + u0 + (np >> 2);
        Wkk[f][np] = Wk[(size_t)f * ZZ + col];
    }
    #pragma unroll
    for (int i = 0; i < 8; ++i) {
        int idx = t + i * 256;        // 2048 = 32 k x 64 f
        int k = idx >> 6, f = idx & 63;
        Wdd[k][f] = Wd[(size_t)(k0 + k) * FF + f];
    }
    __syncthreads();
    #pragma unroll 1
    for (int i = 0; i < 16; ++i) {
        int idx = t + i * 256;
        int k = idx & 31, np = idx >> 5;
        int col = (np & 3) * UU + u0 + (np >> 2);
        float v = Wr[(size_t)(k0 + k) * ZZ + col];
        #pragma unroll
        for (int f = 0; f < 64; ++f) v += Wdd[k][f] * Wkk[f][np];
        int r = n0 + np, kk = k0 + k;
        size_t o = ((size_t)(r >> 5) * NKBD + (kk >> 4)) * 512
                 + (size_t)((((kk >> 3) & 1) * 32 + (r & 31)) * 8 + (kk & 7));
        WT2[o] = (_Float16)v;
    }
}

// bfus: b2 = b + bd@Wk  (4096)
__global__ __launch_bounds__(256) void bfus(
    const float* __restrict__ Wk, const float* __restrict__ b,
    const float* __restrict__ bd, float* __restrict__ b2)
{
    int col = blockIdx.x * 256 + threadIdx.x;
    float v = b[col];
    #pragma unroll 8
    for (int f = 0; f < 64; ++f) v += bd[f] * Wk[(size_t)f * ZZ + col];
    b2[col] = v;
}

// ---------------------------------------------------------------------------
// init: zero h0+c (3MB contiguous), convert x_0 to f16, zero sync counters
// ---------------------------------------------------------------------------
__global__ __launch_bounds__(256) void init_k(
    uint4* __restrict__ zbase, const float* __restrict__ x0,
    _Float16* __restrict__ xF, unsigned int* __restrict__ cnt)
{
    const int b = blockIdx.x, t = threadIdx.x;
    if (b < 768) {
        zbase[(size_t)b * 256 + t] = make_uint4(0u, 0u, 0u, 0u);
    } else if (b < 896) {
        int e = (b - 768) * 256 + t;   // 0..32767
        int bb = e >> 6, f = e & 63;
        xF[e] = (_Float16)x0[(size_t)bb * (TT * FF) + f];
    } else {
        if (t < 16) cnt[t] = 0u;
    }
}

// ---------------------------------------------------------------------------
// One LSTM cell step for a 32x128 tile (verified structure from cell_warm /
// cell_dec): A reg-staged LDS dbuf (raw s_barrier + lgkm-only), W direct
// VGPR 4-slot, 32x32x16 MFMA, C-frag -> z in LDS -> fused gates.
// ---------------------------------------------------------------------------
template<int NCH, int HASX>
__device__ __forceinline__ void cell_step(
    const _Float16* aAx, const _Float16* aAh, const _Float16* __restrict__ pW,
    _Float16* lds, float* z, const float* __restrict__ bias4,
    float* c, _Float16* hFo,
    int t, int lane, int nw, int r0, int u0, int wA, int fra)
{
    uint4 sA[2];
    f32x16 acc;
    #pragma unroll
    for (int i = 0; i < 16; ++i) acc[i] = 0.f;
    f16x8 wf[4][4];

#define LOADA(ch)                                                              \
    {                                                                          \
        sA[(ch) & 1] = (HASX && (ch) == 0)                                     \
                           ? *(const uint4*)aAx                                \
                           : *(const uint4*)(aAh + ((ch) - HASX) * 64);        \
    }
#define LOADW(ch)                                                              \
    {                                                                          \
        _Pragma("unroll")                                                      \
        for (int s = 0; s < 4; ++s)                                            \
            wf[(ch) & 3][s] = *(const f16x8*)(pW + ((ch) * 4 + s) * 512);      \
    }
#define WRITEA(ch)                                                             \
    { *(uint4*)(lds + ((ch) & 1) * CBUF + wA) = sA[(ch) & 1]; }

    LOADA(0) LOADW(0)
    LOADA(1) LOADW(1) LOADW(2)
    WRITEA(0)

    #pragma unroll
    for (int ch = 0; ch < NCH; ++ch) {
        if (ch + 2 < NCH) LOADA(ch + 2)
        if (ch + 3 < NCH) LOADW(ch + 3)
        __builtin_amdgcn_s_waitcnt(0xC07F);   // lgkmcnt(0) only
        __builtin_amdgcn_s_barrier();
        if (ch + 1 < NCH) WRITEA(ch + 1)
        const _Float16* bp = lds + (ch & 1) * CBUF;
        #pragma unroll
        for (int s = 0; s < 4; ++s) {
            f16x8 af = *(const f16x8*)(bp + fra + s * 16);
            acc = __builtin_amdgcn_mfma_f32_32x32x16_f16(af, wf[ch & 3][s], acc, 0, 0, 0);
        }
    }
#undef LOADA
#undef LOADW
#undef WRITEA

    __syncthreads();
    {   // C-frag (col=lane&31, row=(r&3)+8*(r>>2)+4*(lane>>5)) -> z[m][g][u]
        const int l31 = lane & 31;
        const int nloc = nw * 32 + l31;
        const int gs = (nloc & 3) * 33 + (nloc >> 2);
        const int rbase = 4 * (lane >> 5);
        #pragma unroll
        for (int r = 0; r < 16; ++r) {
            int m = rbase + (r & 3) + 8 * (r >> 2);
            z[m * 132 + gs] = acc[r];
        }
    }
    __syncthreads();
    {   // gates: thread (u = t&31), 4 m-rows each
        const int ul = t & 31;
        const int uu = u0 + ul;
        const float bi = bias4[uu], bfr = bias4[UU + uu];
        const float bg = bias4[2 * UU + uu], bo = bias4[3 * UU + uu];
        #pragma unroll
        for (int rep = 0; rep < 4; ++rep) {
            int m = (t >> 5) * 4 + rep;
            float zi = z[m * 132 + ul];
            float zf = z[m * 132 + 33 + ul];
            float zg = z[m * 132 + 66 + ul];
            float zo = z[m * 132 + 99 + ul];
            size_t idx = (size_t)(r0 + m) * UU + uu;
            float cn = sigf(zf + bfr) * c[idx] + sigf(zi + bi) * tanhf(zg + bg);
            c[idx] = cn;
            hFo[idx] = (_Float16)(sigf(zo + bo) * tanhf(cn));
        }
    }
}

// ---------------------------------------------------------------------------
// dense (256 thr): 8 rows/block; out[r][f] = h[r]@Wd + bd (fp32 out only)
// ---------------------------------------------------------------------------
__device__ __forceinline__ void dense_step(
    const _Float16* __restrict__ hF, const float* __restrict__ Wd,
    const float* __restrict__ bd, float* __restrict__ outp,
    char* smem, int rbase)
{
    float* red = (float*)smem;                 // 4 ks x 8 r x 64 f = 8 KB
    const int t = threadIdx.x, f = t & 63, ks = t >> 6;   // ks 0..3
    const _Float16* hb = hF + (size_t)rbase * UU + ks * 256;
    const float* wp = Wd + (size_t)(ks * 256) * FF + f;
    float s[8] = {0.f, 0.f, 0.f, 0.f, 0.f, 0.f, 0.f, 0.f};
    #pragma unroll 2
    for (int v = 0; v < 32; ++v) {
        f16x8 a[8];
        #pragma unroll
        for (int r = 0; r < 8; ++r) a[r] = *(const f16x8*)(hb + r * UU + v * 8);
        #pragma unroll
        for (int j = 0; j < 8; ++j) {
            float wv = wp[(size_t)(v * 8 + j) * FF];
            #pragma unroll
            for (int r = 0; r < 8; ++r) s[r] += (float)a[r][j] * wv;
        }
    }
    #pragma unroll
    for (int r = 0; r < 8; ++r) red[(ks * 8 + r) * 64 + f] = s[r];
    __syncthreads();
    {
        const int q = t >> 6;                  // 0..3 -> rows q and q+4
        #pragma unroll
        for (int h = 0; h < 2; ++h) {
            int r = q + h * 4;
            float vv = bd[f];
            #pragma unroll
            for (int k = 0; k < 4; ++k) vv += red[(k * 8 + r) * 64 + f];
            outp[(size_t)(rbase + r) * (OS * FF) + f] = vv;
        }
    }
}

// ---------------------------------------------------------------------------
// Persistent kernel: 512 blocks (2/CU, exactly co-resident). All 128 warmup
// + 31 decode steps run inside, with per-rtile (32-block) device-scope
// counter barriers between steps. Dense slices for out[s-1] computed by 4
// rotated panels of each rtile group, reading h_{s-1} BEFORE signaling.
// ---------------------------------------------------------------------------
__global__ __launch_bounds__(256, 2) void lstm_persist(
    const float* __restrict__ inputs,
    _Float16* x0F, _Float16* x1F,
    _Float16* hF0, _Float16* hF1, float* cb,
    const _Float16* __restrict__ WT, const float* __restrict__ bias,
    const _Float16* __restrict__ WT2, const float* __restrict__ b2,
    const float* __restrict__ Wd, const float* __restrict__ bd,
    float* __restrict__ out, unsigned int* cnt)
{
    __shared__ __align__(16) char smem[32 * 132 * 4];   // 16896 B
    _Float16* lds = (_Float16*)smem;
    float* z = (float*)smem;

    const int t = threadIdx.x;
    const int lane = t & 63;
    const int nw = t >> 6;
    const int bid = blockIdx.x;
    const int panel = bid & 31, rtile = bid >> 5;   // bid%8 = panel%8 -> 4 panels/XCD (weight L2 locality)
    const int r0 = rtile * 32, u0 = panel * 32;
    const int srow = t >> 3, sseg = t & 7;
    const int wA = srow * CROW + sseg * 8;
    const int fra = (lane & 31) * CROW + (lane >> 5) * 8;

    const size_t aox = (size_t)(r0 + srow) * FF + sseg * 8;
    const size_t aoh = (size_t)(r0 + srow) * UU + sseg * 8;
    const _Float16* pW  = WT  + ((size_t)(panel * 4 + nw) * NKBW) * 512 + lane * 8;
    const _Float16* pW2 = WT2 + ((size_t)(panel * 4 + nw) * NKBD) * 512 + lane * 8;

    unsigned int* mycnt = cnt + rtile;
    unsigned int target = 0;
    _Float16 *hc = hF0, *hn = hF1;

#define GROUP_SYNC()                                                           \
    {                                                                          \
        __syncthreads();                                                       \
        target += 32;                                                          \
        if (t == 0) {                                                          \
            __hip_atomic_fetch_add(mycnt, 1u, __ATOMIC_RELEASE,                \
                                   __HIP_MEMORY_SCOPE_AGENT);                  \
            while (__hip_atomic_load(mycnt, __ATOMIC_RELAXED,                  \
                                     __HIP_MEMORY_SCOPE_AGENT) < target)       \
                __builtin_amdgcn_s_sleep(2);                                   \
            __builtin_amdgcn_fence(__ATOMIC_ACQUIRE, "agent");                 \
        }                                                                      \
        __syncthreads();                                                       \
    }

    // ---- warmup: 128 steps ----
    #pragma unroll 1
    for (int step = 0; step < TT; ++step) {
        const _Float16* xF = (step & 1) ? x1F : x0F;
        _Float16* xnF = (step & 1) ? x0F : x1F;
        cell_step<NCHW, 1>(xF + aox, hc + aoh, pW, lds, z, bias, cb, hn,
                           t, lane, nw, r0, u0, wA, fra);
        // convert x_{step+1}: row bid belongs to this block's rtile group
        if (step + 1 < TT && t < 64) {
            xnF[bid * 64 + t] =
                (_Float16)inputs[(size_t)bid * (TT * FF) + (size_t)(step + 1) * FF + t];
        }
        GROUP_SYNC();
        _Float16* tp = hc; hc = hn; hn = tp;
    }

    // ---- decode: 31 steps; 4 rotated panels/group also do dense(h_{s-1}) ----
    const int dp = (panel - 4 * (rtile & 7)) & 31;
    #pragma unroll 1
    for (int s = 1; s < OS; ++s) {
        cell_step<NCHD, 0>(nullptr, hc + aoh, pW2, lds, z, b2, cb, hn,
                           t, lane, nw, r0, u0, wA, fra);
        if (dp < 4) {
            __syncthreads();   // block-uniform; protects smem z -> red reuse
            dense_step(hc, Wd, bd, out + (size_t)(s - 1) * FF, smem, r0 + 8 * dp);
        }
        GROUP_SYNC();          // also makes h_s visible; h_{s-1} reads all done pre-signal
        _Float16* tp = hc; hc = hn; hn = tp;
    }

    // final dense on h_31 (group-synced by last iteration's barrier)
    if (dp < 4) {
        dense_step(hc, Wd, bd, out + (size_t)(OS - 1) * FF, smem, r0 + 8 * dp);
    }
#undef GROUP_SYNC
}

extern "C" void kernel_launch(void* const* d_in, const int* in_sizes, int n_in,
                              void* d_out, int out_size, void* d_ws, size_t ws_size,
                              hipStream_t stream) {
    const float* inputs = (const float*)d_in[0];
    const float* Wk     = (const float*)d_in[1];
    const float* Wr     = (const float*)d_in[2];
    const float* bias   = (const float*)d_in[3];
    const float* Wd     = (const float*)d_in[4];
    const float* bd     = (const float*)d_in[5];
    float* out = (float*)d_out;

    char* ws = (char*)d_ws;
    _Float16* hF0 = (_Float16*)(ws);                  // 1 MB   (zeroed)
    float*    cb  = (float*)(ws + 1048576);           // 2 MB   (zeroed)
    _Float16* hF1 = (_Float16*)(ws + 3145728);        // 1 MB
    _Float16* WT  = (_Float16*)(ws + 4194304);        // 8,912,896 (warm frag)
    _Float16* WT2 = (_Float16*)(ws + 13107200);       // 8,388,608 (fused frag)
    _Float16* x0F = (_Float16*)(ws + 21495808);       // 64 KB
    _Float16* x1F = (_Float16*)(ws + 21561344);       // 64 KB
    float*    b2  = (float*)(ws + 21626880);          // 16 KB
    unsigned int* cnt = (unsigned int*)(ws + 21643264);  // 64 B (zeroed by init_k)

    wconv<<<dim3(34, 32), 256, 0, stream>>>(Wk, Wr, WT);
    wfus<<<dim3(32, 32), 256, 0, stream>>>(Wk, Wr, Wd, WT2);
    bfus<<<16, 256, 0, stream>>>(Wk, bias, bd, b2);
    init_k<<<897, 256, 0, stream>>>((uint4*)ws, inputs, x0F, cnt);

    // persistent: 512 blocks x 256 thr = 2 blocks/CU on 256 CUs (exact fit,
    // guaranteed by __launch_bounds__(256,2): LDS 16.9KB<=80KB, VGPR<=256)
    lstm_persist<<<512, 256, 0, stream>>>(inputs, x0F, x1F, hF0, hF1, cb,
                                          WT, bias, WT2, b2, Wd, bd, out, cnt);
}

// Round 3
// 4520.754 us; speedup vs baseline: 2.6204x; 2.6204x over previous
//
#include <hip/hip_runtime.h>
#include <math.h>

#define BATCH 512
#define TT    128
#define FF    64
#define UU    1024
#define ZZ    4096
#define OS    32
#define KTOT  1088
#define NCHW  17            // warmup K chunks of 64 (0 = x, 1..16 = h)
#define NCHD  16            // decode K chunks of 64 (h only, K=1024)
#define CROW  72            // A LDS row stride in f16 (64 + 8 pad = 144 B)
#define CBUF  (32 * CROW)   // 2304 f16 = 4608 B per A chunk buffer (BM=32)
#define NKBW  68            // warmup k16 blocks per n-tile (1088/16)
#define NKBD  64            // decode k16 blocks per n-tile (1024/16)
#define ARING 6             // A-stage register ring depth (covers LLC latency)

typedef _Float16 f16x8 __attribute__((ext_vector_type(8)));
typedef float f32x16 __attribute__((ext_vector_type(16)));
typedef float f32x8 __attribute__((ext_vector_type(8)));
typedef unsigned long long u64;

union F16Q { u64 q[2]; f16x8 v; };

__device__ __forceinline__ float sigf(float x) { return 1.0f / (1.0f + expf(-x)); }

// ---------------------------------------------------------------------------
// wconv: [Wk;Wr] (1088x4096 fp32) -> f16 fragment-linear, gate-interleaved
// ---------------------------------------------------------------------------
__global__ __launch_bounds__(256) void wconv(
    const float* __restrict__ Wk, const float* __restrict__ Wr,
    _Float16* __restrict__ WT)
{
    __shared__ float T[32][129];
    const int k0 = blockIdx.x * 32;   // 34
    const int n0 = blockIdx.y * 128;  // 32
    const int u0 = n0 >> 2;
    const int t = threadIdx.x;
    #pragma unroll
    for (int i = 0; i < 16; ++i) {
        int idx = t + i * 256;
        int u = idx & 31, k = (idx >> 5) & 31, g = idx >> 10;
        int krow = k0 + k;
        int col = g * UU + u0 + u;
        float wv = (krow < FF) ? Wk[(size_t)krow * ZZ + col]
                               : Wr[(size_t)(krow - FF) * ZZ + col];
        T[k][u * 4 + g] = wv;
    }
    __syncthreads();
    #pragma unroll
    for (int i = 0; i < 16; ++i) {
        int idx = t + i * 256;
        int k = idx & 31, np = idx >> 5;
        int r = n0 + np, kk = k0 + k;
        size_t o = ((size_t)(r >> 5) * NKBW + (kk >> 4)) * 512
                 + (size_t)((((kk >> 3) & 1) * 32 + (r & 31)) * 8 + (kk & 7));
        WT[o] = (_Float16)T[k][np];
    }
}

// ---------------------------------------------------------------------------
// wfus: WT2 = Wr + Wd@Wk (1024x4096), fragment-linear f16 (NKBD blocks/n-tile)
// ---------------------------------------------------------------------------
__global__ __launch_bounds__(256) void wfus(
    const float* __restrict__ Wk, const float* __restrict__ Wr,
    const float* __restrict__ Wd, _Float16* __restrict__ WT2)
{
    __shared__ float Wkk[64][128];    // [f][np]
    __shared__ float Wdd[32][65];     // [k][f], padded
    const int k0 = blockIdx.x * 32;   // 32 (u-rows)
    const int n0 = blockIdx.y * 128;  // 32
    const int u0 = n0 >> 2;
    const int t = threadIdx.x;
    #pragma unroll
    for (int i = 0; i < 32; ++i) {
        int idx = t + i * 256;        // 8192 = 64 f x 128 np
        int f = idx >> 7, np = idx & 127;
        int col = (np & 3) * UU + u0 + (np >> 2);
        Wkk[f][np] = Wk[(size_t)f * ZZ + col];
    }
    #pragma unroll
    for (int i = 0; i < 8; ++i) {
        int idx = t + i * 256;        // 2048 = 32 k x 64 f
        int k = idx >> 6, f = idx & 63;
        Wdd[k][f] = Wd[(size_t)(k0 + k) * FF + f];
    }
    __syncthreads();
    #pragma unroll 1
    for (int i = 0; i < 16; ++i) {
        int idx = t + i * 256;
        int k = idx & 31, np = idx >> 5;
        int col = (np & 3) * UU + u0 + (np >> 2);
        float v = Wr[(size_t)(k0 + k) * ZZ + col];
        #pragma unroll
        for (int f = 0; f < 64; ++f) v += Wdd[k][f] * Wkk[f][np];
        int r = n0 + np, kk = k0 + k;
        size_t o = ((size_t)(r >> 5) * NKBD + (kk >> 4)) * 512
                 + (size_t)((((kk >> 3) & 1) * 32 + (r & 31)) * 8 + (kk & 7));
        WT2[o] = (_Float16)v;
    }
}

// bfus: b2 = b + bd@Wk  (4096)
__global__ __launch_bounds__(256) void bfus(
    const float* __restrict__ Wk, const float* __restrict__ b,
    const float* __restrict__ bd, float* __restrict__ b2)
{
    int col = blockIdx.x * 256 + threadIdx.x;
    float v = b[col];
    #pragma unroll 8
    for (int f = 0; f < 64; ++f) v += bd[f] * Wk[(size_t)f * ZZ + col];
    b2[col] = v;
}

// ---------------------------------------------------------------------------
// init: zero h0+c (3MB contiguous), zero sync counters
// ---------------------------------------------------------------------------
__global__ __launch_bounds__(256) void init_k(
    uint4* __restrict__ zbase, unsigned int* __restrict__ cnt)
{
    const int b = blockIdx.x, t = threadIdx.x;
    if (b < 768) {
        zbase[(size_t)b * 256 + t] = make_uint4(0u, 0u, 0u, 0u);
    } else {
        if (t < 16) cnt[t * 64] = 0u;        // counters padded 256B apart
    }
}

// ---------------------------------------------------------------------------
// One LSTM cell step for a 32x128 tile. A reg-staged LDS dbuf (raw s_barrier
// + lgkm-only), ARING-deep A register ring (h comes from LLC via agent-scope
// bypass loads -> ~600ns latency to cover), W direct VGPR 4-slot,
// 32x32x16 MFMA, C-frag -> z in LDS -> fused gates.
// h is accessed ONLY via relaxed agent-scope atomics (sc0 sc1, LLC-coherent):
// no fences / cache maintenance anywhere in the step loop. x (warmup chunk 0)
// is read straight from the read-only fp32 inputs tensor and converted in
// registers (no staging buffer, no cross-block x traffic).
// ---------------------------------------------------------------------------
template<int NCH, int HASX>
__device__ __forceinline__ void cell_step(
    const float* aAx, const _Float16* aAh, const _Float16* __restrict__ pW,
    _Float16* lds, float* z, const float* __restrict__ bias4,
    float* c, _Float16* hFo,
    int t, int lane, int nw, int r0, int u0, int wA, int fra)
{
    u64 sA[ARING][2];
    u64 xq[2];
    f32x8 xv;
    f32x16 acc;
    #pragma unroll
    for (int i = 0; i < 16; ++i) acc[i] = 0.f;
    f16x8 wf[4][4];

#define LOADA(ch)                                                              \
    {                                                                          \
        if (!(HASX && (ch) == 0)) {                                            \
            const u64* p = (const u64*)(aAh + ((ch) - HASX) * 64);             \
            sA[(ch) % ARING][0] = __hip_atomic_load(                           \
                p, __ATOMIC_RELAXED, __HIP_MEMORY_SCOPE_AGENT);                \
            sA[(ch) % ARING][1] = __hip_atomic_load(                           \
                p + 1, __ATOMIC_RELAXED, __HIP_MEMORY_SCOPE_AGENT);            \
        }                                                                      \
    }
#define LOADW(ch)                                                              \
    {                                                                          \
        _Pragma("unroll")                                                      \
        for (int s = 0; s < 4; ++s)                                            \
            wf[(ch) & 3][s] = *(const f16x8*)(pW + ((ch) * 4 + s) * 512);      \
    }
#define WRITEA(ch)                                                             \
    {                                                                          \
        u64* q = (u64*)(lds + ((ch) & 1) * CBUF + wA);                         \
        if (HASX && (ch) == 0) {                                               \
            q[0] = xq[0];                                                      \
            q[1] = xq[1];                                                      \
        } else {                                                               \
            q[0] = sA[(ch) % ARING][0];                                        \
            q[1] = sA[(ch) % ARING][1];                                        \
        }                                                                      \
    }

    if (HASX) xv = *(const f32x8*)aAx;      // 2x global_load_dwordx4, cached
    LOADA(0) LOADW(0)
    LOADA(1) LOADW(1) LOADW(2)
    LOADA(2) LOADA(3) LOADA(4) LOADA(5)
    if (HASX) {                              // convert x fp32 -> f16 in regs
        F16Q q;
        #pragma unroll
        for (int j = 0; j < 8; ++j) q.v[j] = (_Float16)xv[j];
        xq[0] = q.q[0]; xq[1] = q.q[1];
    }
    WRITEA(0)

    #pragma unroll
    for (int ch = 0; ch < NCH; ++ch) {
        if (ch + ARING < NCH) LOADA(ch + ARING)
        if (ch + 3 < NCH) LOADW(ch + 3)
        __builtin_amdgcn_s_waitcnt(0xC07F);   // lgkmcnt(0) only
        __builtin_amdgcn_s_barrier();
        if (ch + 1 < NCH) WRITEA(ch + 1)
        const _Float16* bp = lds + (ch & 1) * CBUF;
        #pragma unroll
        for (int s = 0; s < 4; ++s) {
            f16x8 af = *(const f16x8*)(bp + fra + s * 16);
            acc = __builtin_amdgcn_mfma_f32_32x32x16_f16(af, wf[ch & 3][s], acc, 0, 0, 0);
        }
    }
#undef LOADA
#undef LOADW
#undef WRITEA

    __syncthreads();
    {   // C-frag (col=lane&31, row=(r&3)+8*(r>>2)+4*(lane>>5)) -> z[m][g][u]
        const int l31 = lane & 31;
        const int nloc = nw * 32 + l31;
        const int gs = (nloc & 3) * 33 + (nloc >> 2);
        const int rbase = 4 * (lane >> 5);
        #pragma unroll
        for (int r = 0; r < 16; ++r) {
            int m = rbase + (r & 3) + 8 * (r >> 2);
            z[m * 132 + gs] = acc[r];
        }
    }
    __syncthreads();
    {   // gates: thread (u = t&31), 4 m-rows each; h stored via 4B agent-
        // scope bypass stores (pack 2 f16 across lane pairs with shfl_xor)
        const int ul = t & 31;
        const int uu = u0 + ul;
        const float bi = bias4[uu], bfr = bias4[UU + uu];
        const float bg = bias4[2 * UU + uu], bo = bias4[3 * UU + uu];
        #pragma unroll
        for (int rep = 0; rep < 4; ++rep) {
            int m = (t >> 5) * 4 + rep;
            float zi = z[m * 132 + ul];
            float zf = z[m * 132 + 33 + ul];
            float zg = z[m * 132 + 66 + ul];
            float zo = z[m * 132 + 99 + ul];
            size_t idx = (size_t)(r0 + m) * UU + uu;
            float cn = sigf(zf + bfr) * c[idx] + sigf(zi + bi) * tanhf(zg + bg);
            c[idx] = cn;
            unsigned int hv = (unsigned int)__builtin_bit_cast(
                unsigned short, (_Float16)(sigf(zo + bo) * tanhf(cn)));
            unsigned int pv = (unsigned int)__shfl_xor((int)hv, 1, 64);
            if ((ul & 1) == 0) {
                unsigned int word = hv | (pv << 16);
                __hip_atomic_store((unsigned int*)(hFo + idx), word,
                                   __ATOMIC_RELAXED, __HIP_MEMORY_SCOPE_AGENT);
            }
        }
    }
}

// ---------------------------------------------------------------------------
// dense (256 thr): 8 rows/block; out[r][f] = h[r]@Wd + bd (fp32 out only)
// h read via agent-scope bypass loads (h lives at LLC, never in L1/L2).
// ---------------------------------------------------------------------------
__device__ __forceinline__ void dense_step(
    const _Float16* __restrict__ hF, const float* __restrict__ Wd,
    const float* __restrict__ bd, float* __restrict__ outp,
    char* smem, int rbase)
{
    float* red = (float*)smem;                 // 4 ks x 8 r x 64 f = 8 KB
    const int t = threadIdx.x, f = t & 63, ks = t >> 6;   // ks 0..3
    const _Float16* hb = hF + (size_t)rbase * UU + ks * 256;
    const float* wp = Wd + (size_t)(ks * 256) * FF + f;
    float s[8] = {0.f, 0.f, 0.f, 0.f, 0.f, 0.f, 0.f, 0.f};
    #pragma unroll 2
    for (int v = 0; v < 32; ++v) {
        F16Q a[8];
        #pragma unroll
        for (int r = 0; r < 8; ++r) {
            const u64* p = (const u64*)(hb + r * UU + v * 8);
            a[r].q[0] = __hip_atomic_load(p, __ATOMIC_RELAXED,
                                          __HIP_MEMORY_SCOPE_AGENT);
            a[r].q[1] = __hip_atomic_load(p + 1, __ATOMIC_RELAXED,
                                          __HIP_MEMORY_SCOPE_AGENT);
        }
        #pragma unroll
        for (int j = 0; j < 8; ++j) {
            float wv = wp[(size_t)(v * 8 + j) * FF];
            #pragma unroll
            for (int r = 0; r < 8; ++r) s[r] += (float)a[r].v[j] * wv;
        }
    }
    #pragma unroll
    for (int r = 0; r < 8; ++r) red[(ks * 8 + r) * 64 + f] = s[r];
    __syncthreads();
    {
        const int q = t >> 6;                  // 0..3 -> rows q and q+4
        #pragma unroll
        for (int h = 0; h < 2; ++h) {
            int r = q + h * 4;
            float vv = bd[f];
            #pragma unroll
            for (int k = 0; k < 4; ++k) vv += red[(k * 8 + r) * 64 + f];
            outp[(size_t)(rbase + r) * (OS * FF) + f] = vv;
        }
    }
}

// ---------------------------------------------------------------------------
// Persistent kernel: 512 blocks (2/CU, exactly co-resident). All 128 warmup
// + 31 decode steps inside, with per-rtile (32-block) counter barriers:
// relaxed atomics ONLY -> no buffer_wbl2 / buffer_inv, weights stay L2-hot
// across all steps. h flows through LLC via sc0sc1 bypass atomics.
// ---------------------------------------------------------------------------
__global__ __launch_bounds__(256, 2) void lstm_persist(
    const float* __restrict__ inputs,
    _Float16* hF0, _Float16* hF1, float* cb,
    const _Float16* __restrict__ WT, const float* __restrict__ bias,
    const _Float16* __restrict__ WT2, const float* __restrict__ b2,
    const float* __restrict__ Wd, const float* __restrict__ bd,
    float* __restrict__ out, unsigned int* cnt)
{
    __shared__ __align__(16) char smem[32 * 132 * 4];   // 16896 B
    _Float16* lds = (_Float16*)smem;
    float* z = (float*)smem;

    const int t = threadIdx.x;
    const int lane = t & 63;
    const int nw = t >> 6;
    const int bid = blockIdx.x;
    const int panel = bid & 31, rtile = bid >> 5;   // bid%8 -> 4 panels/XCD (weight L2 locality)
    const int r0 = rtile * 32, u0 = panel * 32;
    const int srow = t >> 3, sseg = t & 7;
    const int wA = srow * CROW + sseg * 8;
    const int fra = (lane & 31) * CROW + (lane >> 5) * 8;

    // x: fp32 inputs [B][T][F]; per-step slab offset = step*FF
    const float* aAxBase = inputs + (size_t)(r0 + srow) * (TT * FF) + sseg * 8;
    const size_t aoh = (size_t)(r0 + srow) * UU + sseg * 8;
    const _Float16* pW  = WT  + ((size_t)(panel * 4 + nw) * NKBW) * 512 + lane * 8;
    const _Float16* pW2 = WT2 + ((size_t)(panel * 4 + nw) * NKBD) * 512 + lane * 8;

    unsigned int* mycnt = cnt + rtile * 64;   // 256B-padded counters
    unsigned int target = 0;
    _Float16 *hc = hF0, *hn = hF1;

#define GROUP_SYNC()                                                           \
    {                                                                          \
        __syncthreads();   /* drains vmcnt(0): h stores visible at LLC */      \
        target += 32;                                                          \
        if (t == 0) {                                                          \
            __hip_atomic_fetch_add(mycnt, 1u, __ATOMIC_RELAXED,                \
                                   __HIP_MEMORY_SCOPE_AGENT);                  \
            while (__hip_atomic_load(mycnt, __ATOMIC_RELAXED,                  \
                                     __HIP_MEMORY_SCOPE_AGENT) < target)       \
                __builtin_amdgcn_s_sleep(4);                                   \
        }                                                                      \
        __syncthreads();                                                       \
    }

    // ---- warmup: 128 steps ----
    #pragma unroll 1
    for (int step = 0; step < TT; ++step) {
        cell_step<NCHW, 1>(aAxBase + (size_t)step * FF,
                           hc + aoh, pW, lds, z, bias, cb, hn,
                           t, lane, nw, r0, u0, wA, fra);
        GROUP_SYNC();
        _Float16* tp = hc; hc = hn; hn = tp;
    }

    // ---- decode: 31 steps; 4 rotated panels/group also do dense(h_{s-1}) ----
    const int dp = (panel - 4 * (rtile & 7)) & 31;
    #pragma unroll 1
    for (int s = 1; s < OS; ++s) {
        cell_step<NCHD, 0>(nullptr, hc + aoh, pW2, lds, z, b2, cb, hn,
                           t, lane, nw, r0, u0, wA, fra);
        if (dp < 4) {
            __syncthreads();   // block-uniform; protects smem z -> red reuse
            dense_step(hc, Wd, bd, out + (size_t)(s - 1) * FF, smem, r0 + 8 * dp);
        }
        GROUP_SYNC();          // h_{s-1} reads (cell + dense) all done pre-signal
        _Float16* tp = hc; hc = hn; hn = tp;
    }

    // final dense on h_31 (group-synced by last iteration's barrier)
    if (dp < 4) {
        dense_step(hc, Wd, bd, out + (size_t)(OS - 1) * FF, smem, r0 + 8 * dp);
    }
#undef GROUP_SYNC
}

extern "C" void kernel_launch(void* const* d_in, const int* in_sizes, int n_in,
                              void* d_out, int out_size, void* d_ws, size_t ws_size,
                              hipStream_t stream) {
    const float* inputs = (const float*)d_in[0];
    const float* Wk     = (const float*)d_in[1];
    const float* Wr     = (const float*)d_in[2];
    const float* bias   = (const float*)d_in[3];
    const float* Wd     = (const float*)d_in[4];
    const float* bd     = (const float*)d_in[5];
    float* out = (float*)d_out;

    char* ws = (char*)d_ws;
    _Float16* hF0 = (_Float16*)(ws);                  // 1 MB   (zeroed)
    float*    cb  = (float*)(ws + 1048576);           // 2 MB   (zeroed)
    _Float16* hF1 = (_Float16*)(ws + 3145728);        // 1 MB
    _Float16* WT  = (_Float16*)(ws + 4194304);        // 8,912,896 (warm frag)
    _Float16* WT2 = (_Float16*)(ws + 13107200);       // 8,388,608 (fused frag)
    float*    b2  = (float*)(ws + 21495808);          // 16 KB
    unsigned int* cnt = (unsigned int*)(ws + 21512192);  // 4 KB (zeroed by init_k)

    wconv<<<dim3(34, 32), 256, 0, stream>>>(Wk, Wr, WT);
    wfus<<<dim3(32, 32), 256, 0, stream>>>(Wk, Wr, Wd, WT2);
    bfus<<<16, 256, 0, stream>>>(Wk, bias, bd, b2);
    init_k<<<769, 256, 0, stream>>>((uint4*)ws, cnt);

    // persistent: 512 blocks x 256 thr = 2 blocks/CU on 256 CUs (exact fit)
    lstm_persist<<<512, 256, 0, stream>>>(inputs, hF0, hF1, cb,
                                          WT, bias, WT2, b2, Wd, bd, out, cnt);
}